// Round 8
// baseline (545.189 us; speedup 1.0000x reference)
//
#include <hip/hip_runtime.h>
#include <cstdint>
#include <cstddef>

#define P_DIM 8
#define U_DIM 256
#define V_DIM 256
#define F_DIM 12544   // 256*49

typedef __attribute__((ext_vector_type(8))) short short8;
typedef __attribute__((ext_vector_type(8))) _Float16 half8;
typedef __attribute__((ext_vector_type(4))) float f32x4;

#define MFMA16B(a, b, c) __builtin_amdgcn_mfma_f32_16x16x32_bf16((a), (b), (c), 0, 0, 0)
#define MFMA16H(a, b, c) __builtin_amdgcn_mfma_f32_16x16x32_f16((a), (b), (c), 0, 0, 0)

__device__ __forceinline__ unsigned short f2bf(float x) {      // RNE (for fvT/score)
  unsigned u = __builtin_bit_cast(unsigned, x);
  u += 0x7FFFu + ((u >> 16) & 1u);
  return (unsigned short)(u >> 16);
}

// 8x fp32 -> 8x fp16 (RNE), packed into uint4
__device__ __forceinline__ uint4 cvt8h(float4 a, float4 b) {
  float x[8] = {a.x, a.y, a.z, a.w, b.x, b.y, b.z, b.w};
  unsigned w[4];
  #pragma unroll
  for (int i = 0; i < 4; ++i) {
    unsigned short lo = __builtin_bit_cast(unsigned short, (_Float16)x[2 * i]);
    unsigned short hi = __builtin_bit_cast(unsigned short, (_Float16)x[2 * i + 1]);
    w[i] = (unsigned)lo | ((unsigned)hi << 16);
  }
  return uint4{w[0], w[1], w[2], w[3]};
}

// ---------------------------------------------------------------------------
// 1) prep_fv: reads fv ONCE; writes fvT bf16 [p][f][v] + fp32 vv partials
// ---------------------------------------------------------------------------
__global__ __launch_bounds__(256) void prep_fv(const float* __restrict__ fv,
                                               unsigned short* __restrict__ fvT,
                                               float* __restrict__ vvpart) {
  __shared__ unsigned short tile[64][65];
  __shared__ float vvp[64];
  int f0 = blockIdx.x * 64, v0 = blockIdx.y * 64, p = blockIdx.z;
  const float* src = fv + (size_t)p * V_DIM * F_DIM;
  int t = threadIdx.x;
  #pragma unroll
  for (int i = 0; i < 4; ++i) {
    int g = t + i * 256;                     // 0..1023
    int r = g >> 4;                          // v row 0..63
    int c4 = (g & 15) * 4;                   // f col
    float4 x = *(const float4*)(src + (size_t)(v0 + r) * F_DIM + f0 + c4);
    tile[r][c4 + 0] = f2bf(x.x);
    tile[r][c4 + 1] = f2bf(x.y);
    tile[r][c4 + 2] = f2bf(x.z);
    tile[r][c4 + 3] = f2bf(x.w);
    float ps = x.x * x.x + x.y * x.y + x.z * x.z + x.w * x.w;
    ps += __shfl_xor(ps, 1); ps += __shfl_xor(ps, 2);
    ps += __shfl_xor(ps, 4); ps += __shfl_xor(ps, 8);
    if ((t & 15) == 0) vvp[r] = ps;
  }
  __syncthreads();
  if (t < 64)
    vvpart[((size_t)blockIdx.x * P_DIM + p) * V_DIM + v0 + t] = vvp[t];
  unsigned short* dst = fvT + (size_t)p * F_DIM * V_DIM;
  #pragma unroll
  for (int i = 0; i < 2; ++i) {
    int g = t + i * 256;                     // 0..511
    int f = g >> 3;                          // 0..63
    int v8 = (g & 7) * 8;
    short8 o;
    #pragma unroll
    for (int j = 0; j < 8; ++j) o[j] = (short)tile[v8 + j][f];
    *(short8*)(dst + (size_t)(f0 + f) * V_DIM + v0 + v8) = o;
  }
}

// ---------------------------------------------------------------------------
// 2) vv_reduce v2: 32 blocks, 4-way k-split per block (was 8-block strided)
// ---------------------------------------------------------------------------
__global__ __launch_bounds__(256) void vv_reduce(const float* __restrict__ vvpart,
                                                 float* __restrict__ vv) {
  int p = blockIdx.x >> 2;
  int vb = (blockIdx.x & 3) * 64;
  int vl = threadIdx.x & 63;
  int v = vb + vl;
  int js = threadIdx.x >> 6;                 // 0..3
  float s = 0.f;
  for (int j = js; j < F_DIM / 64; j += 4)
    s += vvpart[((size_t)j * P_DIM + p) * V_DIM + v];
  __shared__ float red[4][64];
  red[js][vl] = s;
  __syncthreads();
  if (threadIdx.x < 64)
    vv[p * V_DIM + v] = red[0][vl] + red[1][vl] + red[2][vl] + red[3][vl];
}

// ---------------------------------------------------------------------------
// 3) copy feat_u -> out[0 : P*U*F]
// ---------------------------------------------------------------------------
__global__ __launch_bounds__(256) void copy_kernel(const float4* __restrict__ src,
                                                   float4* __restrict__ dst, int n4) {
  for (int i = blockIdx.x * 256 + threadIdx.x; i < n4; i += gridDim.x * 256)
    dst[i] = src[i];
}

// ---------------------------------------------------------------------------
// 4) uv_gemm v7: single-MFMA fp16 path. 128x128 tile, BK=64, 256 thr,
//    32 KB LDS -> 4 blocks/CU. Reg-prefetch next K-tile under MFMA.
//    fp16 RNE logit error (3sigma) ~0.027 vs threshold 0.108.
// ---------------------------------------------------------------------------
__global__ __launch_bounds__(256, 4) void uv_gemm(const float* __restrict__ fu,
                                                  const float* __restrict__ fv,
                                                  float* __restrict__ part,
                                                  int splitk, int chunk) {
  // bijective XCD chunk swizzle (m204)
  int nwg = gridDim.x;
  int q = nwg >> 3, r = nwg & 7;
  int xcd = blockIdx.x & 7, ofs = blockIdx.x >> 3;
  int wgid = (xcd < r ? xcd * (q + 1) : r * (q + 1) + (xcd - r) * q) + ofs;
  int nt = wgid & 1, mt = (wgid >> 1) & 1, p = (wgid >> 2) & 7, ks = wgid >> 5;

  const float* A = fu + ((size_t)p * U_DIM + mt * 128) * F_DIM;
  const float* B = fv + ((size_t)p * V_DIM + nt * 128) * F_DIM;
  int k0 = ks * chunk;
  int nkt = chunk >> 6;

  __shared__ short AS[128 * 64], BS[128 * 64];   // 32 KB total (fp16)
  char* Ap = (char*)AS; char* Bp = (char*)BS;

  int tid = threadIdx.x, lane = tid & 63, wid = tid >> 6;
  int wm = wid >> 1, wn = wid & 1;           // 2x2 waves, 64x64 each
  int rl = lane & 15;
  f32x4 acc[4][4] = {};
  float4 ra[8], rb[8];

#define LOAD_TILE(kg)                                                          \
  do {                                                                         \
    _Pragma("unroll") for (int j = 0; j < 4; ++j) {                            \
      int g = tid + j * 256; int rr = g >> 3; int c8 = (g & 7) * 8;            \
      const float* s = A + (size_t)rr * F_DIM + (kg) + c8;                     \
      ra[2 * j] = *(const float4*)s; ra[2 * j + 1] = *(const float4*)(s + 4);  \
      const float* s2 = B + (size_t)rr * F_DIM + (kg) + c8;                    \
      rb[2 * j] = *(const float4*)s2; rb[2 * j + 1] = *(const float4*)(s2 + 4);\
    }                                                                          \
  } while (0)

  LOAD_TILE(k0);
  for (int kt = 0; kt < nkt; ++kt) {
    #pragma unroll
    for (int j = 0; j < 4; ++j) {
      int g = tid + j * 256;
      int rr = g >> 3;
      int off = (rr * 128 + (g & 7) * 16) ^ ((rr & 7) << 4);
      *(uint4*)(Ap + off) = cvt8h(ra[2 * j], ra[2 * j + 1]);
      *(uint4*)(Bp + off) = cvt8h(rb[2 * j], rb[2 * j + 1]);
    }
    __syncthreads();
    if (kt + 1 < nkt) LOAD_TILE(k0 + (kt + 1) * 64);   // prefetch under MFMA
    #pragma unroll
    for (int kk = 0; kk < 2; ++kk) {
      int kbyte = kk * 64 + (lane >> 4) * 16;
      half8 ah[4], bh[4];
      #pragma unroll
      for (int m = 0; m < 4; ++m) {
        int row = wm * 64 + m * 16 + rl;
        int off = (row * 128 + kbyte) ^ ((row & 7) << 4);
        ah[m] = *(const half8*)(Ap + off);
      }
      #pragma unroll
      for (int n = 0; n < 4; ++n) {
        int row = wn * 64 + n * 16 + rl;
        int off = (row * 128 + kbyte) ^ ((row & 7) << 4);
        bh[n] = *(const half8*)(Bp + off);
      }
      #pragma unroll
      for (int m = 0; m < 4; ++m)
        #pragma unroll
        for (int n = 0; n < 4; ++n)
          acc[m][n] = MFMA16H(ah[m], bh[n], acc[m][n]);
    }
    __syncthreads();
  }
#undef LOAD_TILE
  float* dst = part + ((size_t)ks * P_DIM + p) * U_DIM * V_DIM;
  int rq = lane >> 4;
  #pragma unroll
  for (int m = 0; m < 4; ++m)
    #pragma unroll
    for (int n = 0; n < 4; ++n)
      #pragma unroll
      for (int i = 0; i < 4; ++i) {
        int u = mt * 128 + wm * 64 + m * 16 + rq * 4 + i;
        int v = nt * 128 + wn * 64 + n * 16 + rl;
        dst[(size_t)u * V_DIM + v] = acc[m][n][i];
      }
}

// ---------------------------------------------------------------------------
// 5) reduce partials + softmax over v -> bf16 score.  logit = 0.1*vv - 0.2*uv
// ---------------------------------------------------------------------------
__global__ __launch_bounds__(256) void reduce_softmax(const float* __restrict__ part,
                                                      const float* __restrict__ vv,
                                                      unsigned short* __restrict__ score,
                                                      int splitk) {
  int u = blockIdx.x & 255, p = blockIdx.x >> 8;
  int v = threadIdx.x;
  size_t base = ((size_t)p * U_DIM + u) * V_DIM + v;
  float s = 0.f;
  for (int k = 0; k < splitk; ++k)
    s += part[(size_t)k * (P_DIM * U_DIM * V_DIM) + base];
  float logit = 0.1f * vv[p * V_DIM + v] - 0.2f * s;
  float m = logit;
  #pragma unroll
  for (int off = 32; off >= 1; off >>= 1) m = fmaxf(m, __shfl_xor(m, off));
  __shared__ float red[4], red2[4];
  int lane = v & 63, wid = v >> 6;
  if (lane == 0) red[wid] = m;
  __syncthreads();
  m = fmaxf(fmaxf(red[0], red[1]), fmaxf(red[2], red[3]));
  float e = __expf(logit - m);
  float tsum = e;
  #pragma unroll
  for (int off = 32; off >= 1; off >>= 1) tsum += __shfl_xor(tsum, off);
  if (lane == 0) red2[wid] = tsum;
  __syncthreads();
  tsum = red2[0] + red2[1] + red2[2] + red2[3];
  score[base] = f2bf(e / tsum);
}

// ---------------------------------------------------------------------------
// 6) pv_gemm: UNCHANGED structure + DIAGNOSTIC rep-amplification (reps=4,
//    exact pow2 scale) to surface its counter row in top-5.
// ---------------------------------------------------------------------------
__global__ __launch_bounds__(512) void pv_gemm(const unsigned short* __restrict__ score,
                                               const unsigned short* __restrict__ fvT,
                                               float* __restrict__ outneg,
                                               int reps, float scale) {
  int bx = blockIdx.x;                       // f tile 0..97
  int p = blockIdx.y;
  int n0 = bx * 128;
  const unsigned short* Sc = score + (size_t)p * U_DIM * V_DIM;
  const unsigned short* Bt = fvT + ((size_t)p * F_DIM + n0) * V_DIM;
  __shared__ short BsS[128 * 32];            // 8 KB
  char* Bsp = (char*)BsS;
  int tid = threadIdx.x, lane = tid & 63, wid = tid >> 6;
  int wm = wid >> 2, wn = wid & 3;           // wave tile 128x32
  int rl = lane & 15, rq = lane >> 4;
  f32x4 acc[8][2] = {};

  for (int rep = 0; rep < reps; ++rep) {
    for (int kb = 0; kb < V_DIM; kb += 32) {
      {
        int row = tid >> 2;
        int c = tid & 3;
        short8 x = *(const short8*)(Bt + (size_t)row * V_DIM + kb + c * 8);
        int off = row * 64 + ((c ^ ((row >> 1) & 3)) * 16);
        *(short8*)(Bsp + off) = x;
      }
      __syncthreads();
      short8 a[8], b[2];
      #pragma unroll
      for (int m = 0; m < 8; ++m)
        a[m] = *(const short8*)(Sc + (size_t)(wm * 128 + m * 16 + rl) * V_DIM
                                + kb + rq * 8);
      #pragma unroll
      for (int n = 0; n < 2; ++n) {
        int f = wn * 32 + n * 16 + rl;
        int off = f * 64 + ((rq ^ ((f >> 1) & 3)) * 16);
        b[n] = *(const short8*)(Bsp + off);
      }
      #pragma unroll
      for (int m = 0; m < 8; ++m)
        #pragma unroll
        for (int n = 0; n < 2; ++n)
          acc[m][n] = MFMA16B(a[m], b[n], acc[m][n]);
      __syncthreads();
    }
  }
  #pragma unroll
  for (int m = 0; m < 8; ++m)
    #pragma unroll
    for (int n = 0; n < 2; ++n)
      #pragma unroll
      for (int i = 0; i < 4; ++i) {
        int u = wm * 128 + m * 16 + rq * 4 + i;
        int f = n0 + wn * 32 + n * 16 + rl;
        outneg[((size_t)p * U_DIM + u) * F_DIM + f] = acc[m][n][i] * scale;
      }
}

// ---------------------------------------------------------------------------
extern "C" void kernel_launch(void* const* d_in, const int* in_sizes, int n_in,
                              void* d_out, int out_size, void* d_ws, size_t ws_size,
                              hipStream_t stream) {
  const float* fu = (const float*)d_in[0];
  const float* fv = (const float*)d_in[1];
  float* out = (float*)d_out;
  char* ws = (char*)d_ws;

  // ws: vv 8KB | score 1MB | fvT 51.4MB | vvpart 1.6MB | part (splitk*2MB)
  float* vv = (float*)ws;
  unsigned short* score = (unsigned short*)(ws + 8192);
  unsigned short* fvT = (unsigned short*)(ws + 8192 + 1048576);
  size_t vvpartBase = 8192 + 1048576 + (size_t)P_DIM * F_DIM * V_DIM * 2;
  float* vvpart = (float*)(ws + vvpartBase);
  size_t partBase = vvpartBase + (size_t)(F_DIM / 64) * P_DIM * V_DIM * 4;
  float* part = (float*)(ws + partBase);

  const size_t puv4 = (size_t)P_DIM * U_DIM * V_DIM * 4;
  int splitk = 1;
  const int cands[5] = {14, 7, 4, 2, 1};
  for (int i = 0; i < 5; ++i) {
    if (partBase + (size_t)cands[i] * puv4 <= ws_size) { splitk = cands[i]; break; }
  }
  int chunk = F_DIM / splitk;                // multiple of 64 for all candidates

  const int PV_REPS = 4;                     // diagnostic amplification (pow2!)
  const float PV_SCALE = 1.0f / PV_REPS;

  prep_fv<<<dim3(F_DIM / 64, V_DIM / 64, P_DIM), 256, 0, stream>>>(fv, fvT, vvpart);
  vv_reduce<<<P_DIM * 4, 256, 0, stream>>>(vvpart, vv);
  int n4 = (P_DIM * U_DIM * F_DIM) / 4;
  copy_kernel<<<2048, 256, 0, stream>>>((const float4*)fu, (float4*)out, n4);
  uv_gemm<<<splitk * 32, 256, 0, stream>>>(fu, fv, part, splitk, chunk);
  reduce_softmax<<<P_DIM * U_DIM, 256, 0, stream>>>(part, vv, score, splitk);
  pv_gemm<<<dim3(F_DIM / 128, P_DIM), 512, 0, stream>>>(
      score, fvT, out + (size_t)P_DIM * U_DIM * F_DIM, PV_REPS, PV_SCALE);
}

// Round 9
// 205.096 us; speedup vs baseline: 2.6582x; 2.6582x over previous
//
#include <hip/hip_runtime.h>
#include <cstdint>
#include <cstddef>

#define P_DIM 8
#define U_DIM 256
#define V_DIM 256
#define F_DIM 12544   // 256*49

typedef __attribute__((ext_vector_type(8))) short short8;
typedef __attribute__((ext_vector_type(8))) _Float16 half8;
typedef __attribute__((ext_vector_type(4))) float f32x4;

#define MFMA16B(a, b, c) __builtin_amdgcn_mfma_f32_16x16x32_bf16((a), (b), (c), 0, 0, 0)
#define MFMA16H(a, b, c) __builtin_amdgcn_mfma_f32_16x16x32_f16((a), (b), (c), 0, 0, 0)

__device__ __forceinline__ unsigned short f2bf(float x) {      // RNE (for fvT/score)
  unsigned u = __builtin_bit_cast(unsigned, x);
  u += 0x7FFFu + ((u >> 16) & 1u);
  return (unsigned short)(u >> 16);
}

// 8x fp32 -> 8x fp16 (RNE), packed into uint4
__device__ __forceinline__ uint4 cvt8h(float4 a, float4 b) {
  float x[8] = {a.x, a.y, a.z, a.w, b.x, b.y, b.z, b.w};
  unsigned w[4];
  #pragma unroll
  for (int i = 0; i < 4; ++i) {
    unsigned short lo = __builtin_bit_cast(unsigned short, (_Float16)x[2 * i]);
    unsigned short hi = __builtin_bit_cast(unsigned short, (_Float16)x[2 * i + 1]);
    w[i] = (unsigned)lo | ((unsigned)hi << 16);
  }
  return uint4{w[0], w[1], w[2], w[3]};
}

// ---------------------------------------------------------------------------
// 1) prep_fv: reads fv ONCE; writes fvT bf16 [p][f][v] + fp32 vv partials
// ---------------------------------------------------------------------------
__global__ __launch_bounds__(256) void prep_fv(const float* __restrict__ fv,
                                               unsigned short* __restrict__ fvT,
                                               float* __restrict__ vvpart) {
  __shared__ unsigned short tile[64][65];
  __shared__ float vvp[64];
  int f0 = blockIdx.x * 64, v0 = blockIdx.y * 64, p = blockIdx.z;
  const float* src = fv + (size_t)p * V_DIM * F_DIM;
  int t = threadIdx.x;
  #pragma unroll
  for (int i = 0; i < 4; ++i) {
    int g = t + i * 256;                     // 0..1023
    int r = g >> 4;                          // v row 0..63
    int c4 = (g & 15) * 4;                   // f col
    float4 x = *(const float4*)(src + (size_t)(v0 + r) * F_DIM + f0 + c4);
    tile[r][c4 + 0] = f2bf(x.x);
    tile[r][c4 + 1] = f2bf(x.y);
    tile[r][c4 + 2] = f2bf(x.z);
    tile[r][c4 + 3] = f2bf(x.w);
    float ps = x.x * x.x + x.y * x.y + x.z * x.z + x.w * x.w;
    ps += __shfl_xor(ps, 1); ps += __shfl_xor(ps, 2);
    ps += __shfl_xor(ps, 4); ps += __shfl_xor(ps, 8);
    if ((t & 15) == 0) vvp[r] = ps;
  }
  __syncthreads();
  if (t < 64)
    vvpart[((size_t)blockIdx.x * P_DIM + p) * V_DIM + v0 + t] = vvp[t];
  unsigned short* dst = fvT + (size_t)p * F_DIM * V_DIM;
  #pragma unroll
  for (int i = 0; i < 2; ++i) {
    int g = t + i * 256;                     // 0..511
    int f = g >> 3;                          // 0..63
    int v8 = (g & 7) * 8;
    short8 o;
    #pragma unroll
    for (int j = 0; j < 8; ++j) o[j] = (short)tile[v8 + j][f];
    *(short8*)(dst + (size_t)(f0 + f) * V_DIM + v0 + v8) = o;
  }
}

// ---------------------------------------------------------------------------
// 2) vv_reduce: 32 blocks, 4-way k-split per block
// ---------------------------------------------------------------------------
__global__ __launch_bounds__(256) void vv_reduce(const float* __restrict__ vvpart,
                                                 float* __restrict__ vv) {
  int p = blockIdx.x >> 2;
  int vb = (blockIdx.x & 3) * 64;
  int vl = threadIdx.x & 63;
  int v = vb + vl;
  int js = threadIdx.x >> 6;                 // 0..3
  float s = 0.f;
  for (int j = js; j < F_DIM / 64; j += 4)
    s += vvpart[((size_t)j * P_DIM + p) * V_DIM + v];
  __shared__ float red[4][64];
  red[js][vl] = s;
  __syncthreads();
  if (threadIdx.x < 64)
    vv[p * V_DIM + v] = red[0][vl] + red[1][vl] + red[2][vl] + red[3][vl];
}

// ---------------------------------------------------------------------------
// 3) copy feat_u -> out[0 : P*U*F]
// ---------------------------------------------------------------------------
__global__ __launch_bounds__(256) void copy_kernel(const float4* __restrict__ src,
                                                   float4* __restrict__ dst, int n4) {
  for (int i = blockIdx.x * 256 + threadIdx.x; i < n4; i += gridDim.x * 256)
    dst[i] = src[i];
}

// ---------------------------------------------------------------------------
// 4) uv_gemm v9: fp16 single-MFMA, 128x128 tile, BK=64, 256 thr, 32 KB LDS.
//    __launch_bounds__(256,2): cap 256 VGPR -> NO SPILLS (R8's (256,4) spilled
//    to scratch, 2x regression). Natural VGPR ~110-130 -> up to 4 blk/CU.
// ---------------------------------------------------------------------------
__global__ __launch_bounds__(256, 2) void uv_gemm(const float* __restrict__ fu,
                                                  const float* __restrict__ fv,
                                                  float* __restrict__ part,
                                                  int splitk, int chunk) {
  // bijective XCD chunk swizzle (m204)
  int nwg = gridDim.x;
  int q = nwg >> 3, r = nwg & 7;
  int xcd = blockIdx.x & 7, ofs = blockIdx.x >> 3;
  int wgid = (xcd < r ? xcd * (q + 1) : r * (q + 1) + (xcd - r) * q) + ofs;
  int nt = wgid & 1, mt = (wgid >> 1) & 1, p = (wgid >> 2) & 7, ks = wgid >> 5;

  const float* A = fu + ((size_t)p * U_DIM + mt * 128) * F_DIM;
  const float* B = fv + ((size_t)p * V_DIM + nt * 128) * F_DIM;
  int k0 = ks * chunk;
  int nkt = chunk >> 6;

  __shared__ short AS[128 * 64], BS[128 * 64];   // 32 KB total (fp16)
  char* Ap = (char*)AS; char* Bp = (char*)BS;

  int tid = threadIdx.x, lane = tid & 63, wid = tid >> 6;
  int wm = wid >> 1, wn = wid & 1;           // 2x2 waves, 64x64 each
  int rl = lane & 15;
  f32x4 acc[4][4] = {};
  float4 ra[8], rb[8];

#define LOAD_TILE(kg)                                                          \
  do {                                                                         \
    _Pragma("unroll") for (int j = 0; j < 4; ++j) {                            \
      int g = tid + j * 256; int rr = g >> 3; int c8 = (g & 7) * 8;            \
      const float* s = A + (size_t)rr * F_DIM + (kg) + c8;                     \
      ra[2 * j] = *(const float4*)s; ra[2 * j + 1] = *(const float4*)(s + 4);  \
      const float* s2 = B + (size_t)rr * F_DIM + (kg) + c8;                    \
      rb[2 * j] = *(const float4*)s2; rb[2 * j + 1] = *(const float4*)(s2 + 4);\
    }                                                                          \
  } while (0)

  LOAD_TILE(k0);
  for (int kt = 0; kt < nkt; ++kt) {
    #pragma unroll
    for (int j = 0; j < 4; ++j) {
      int g = tid + j * 256;
      int rr = g >> 3;
      int off = (rr * 128 + (g & 7) * 16) ^ ((rr & 7) << 4);
      *(uint4*)(Ap + off) = cvt8h(ra[2 * j], ra[2 * j + 1]);
      *(uint4*)(Bp + off) = cvt8h(rb[2 * j], rb[2 * j + 1]);
    }
    __syncthreads();
    if (kt + 1 < nkt) LOAD_TILE(k0 + (kt + 1) * 64);   // prefetch under MFMA
    #pragma unroll
    for (int kk = 0; kk < 2; ++kk) {
      int kbyte = kk * 64 + (lane >> 4) * 16;
      half8 ah[4], bh[4];
      #pragma unroll
      for (int m = 0; m < 4; ++m) {
        int row = wm * 64 + m * 16 + rl;
        int off = (row * 128 + kbyte) ^ ((row & 7) << 4);
        ah[m] = *(const half8*)(Ap + off);
      }
      #pragma unroll
      for (int n = 0; n < 4; ++n) {
        int row = wn * 64 + n * 16 + rl;
        int off = (row * 128 + kbyte) ^ ((row & 7) << 4);
        bh[n] = *(const half8*)(Bp + off);
      }
      #pragma unroll
      for (int m = 0; m < 4; ++m)
        #pragma unroll
        for (int n = 0; n < 4; ++n)
          acc[m][n] = MFMA16H(ah[m], bh[n], acc[m][n]);
    }
    __syncthreads();
  }
#undef LOAD_TILE
  float* dst = part + ((size_t)ks * P_DIM + p) * U_DIM * V_DIM;
  int rq = lane >> 4;
  #pragma unroll
  for (int m = 0; m < 4; ++m)
    #pragma unroll
    for (int n = 0; n < 4; ++n)
      #pragma unroll
      for (int i = 0; i < 4; ++i) {
        int u = mt * 128 + wm * 64 + m * 16 + rq * 4 + i;
        int v = nt * 128 + wn * 64 + n * 16 + rl;
        dst[(size_t)u * V_DIM + v] = acc[m][n][i];
      }
}

// ---------------------------------------------------------------------------
// 5) reduce partials + softmax over v -> bf16 score.  logit = 0.1*vv - 0.2*uv
// ---------------------------------------------------------------------------
__global__ __launch_bounds__(256) void reduce_softmax(const float* __restrict__ part,
                                                      const float* __restrict__ vv,
                                                      unsigned short* __restrict__ score,
                                                      int splitk) {
  int u = blockIdx.x & 255, p = blockIdx.x >> 8;
  int v = threadIdx.x;
  size_t base = ((size_t)p * U_DIM + u) * V_DIM + v;
  float s = 0.f;
  for (int k = 0; k < splitk; ++k)
    s += part[(size_t)k * (P_DIM * U_DIM * V_DIM) + base];
  float logit = 0.1f * vv[p * V_DIM + v] - 0.2f * s;
  float m = logit;
  #pragma unroll
  for (int off = 32; off >= 1; off >>= 1) m = fmaxf(m, __shfl_xor(m, off));
  __shared__ float red[4], red2[4];
  int lane = v & 63, wid = v >> 6;
  if (lane == 0) red[wid] = m;
  __syncthreads();
  m = fmaxf(fmaxf(red[0], red[1]), fmaxf(red[2], red[3]));
  float e = __expf(logit - m);
  float tsum = e;
  #pragma unroll
  for (int off = 32; off >= 1; off >>= 1) tsum += __shfl_xor(tsum, off);
  if (lane == 0) red2[wid] = tsum;
  __syncthreads();
  tsum = red2[0] + red2[1] + red2[2] + red2[3];
  score[base] = f2bf(e / tsum);
}

// ---------------------------------------------------------------------------
// 6) pv_gemm v2: block = 256u x 128f x FULL K=256.
//    A (score) hoisted to registers ONCE (a[2][8] per wave, L2-resident);
//    fvT tile (128f x 256v, 64 KB) staged to LDS ONCE (XOR-swizzled);
//    one barrier, then 1024 MFMAs/block with LDS-only operand reads.
//    Kills R8's per-K-step global-latency exposure (MfmaUtil 8%, VALU 4%).
//    grid (98, 8) x 512 threads; 8 waves each own 32 u-rows.
// ---------------------------------------------------------------------------
__global__ __launch_bounds__(512, 1) void pv_gemm(const unsigned short* __restrict__ score,
                                                  const unsigned short* __restrict__ fvT,
                                                  float* __restrict__ outneg) {
  int bx = blockIdx.x;                       // f tile 0..97
  int p = blockIdx.y;
  int n0 = bx * 128;
  const unsigned short* Sc = score + (size_t)p * U_DIM * V_DIM;
  const unsigned short* Bt = fvT + ((size_t)p * F_DIM + n0) * V_DIM;
  __shared__ short Bs[128 * 256];            // 64 KB
  char* Bsp = (char*)Bs;
  int tid = threadIdx.x, lane = tid & 63, wid = tid >> 6;
  int rl = lane & 15, rq = lane >> 4;

  // A-frags for the wave's 32 u-rows, all K=256: issued first (L2 latency
  // overlaps the fvT staging below).
  short8 a[2][8];
  #pragma unroll
  for (int m = 0; m < 2; ++m)
    #pragma unroll
    for (int k = 0; k < 8; ++k)
      a[m][k] = *(const short8*)(Sc + (size_t)(wid * 32 + m * 16 + rl) * V_DIM
                                 + k * 32 + rq * 8);

  // stage fvT tile: 128 f-rows x 256 v (512 B/row), swizzle byte^=(row&7)<<4
  {
    int row = tid >> 2;                      // 0..127
    int seg = (tid & 3) * 128;               // byte offset within row
    const char* src = (const char*)(Bt + (size_t)row * V_DIM) + seg;
    char* dstrow = Bsp + row * 512;
    int swz = (row & 7) << 4;
    #pragma unroll
    for (int j = 0; j < 8; ++j) {
      uint4 x = *(const uint4*)(src + j * 16);
      *(uint4*)(dstrow + ((seg + j * 16) ^ swz)) = x;
    }
  }
  __syncthreads();

  f32x4 acc[2][8] = {};
  #pragma unroll
  for (int k = 0; k < 8; ++k) {
    #pragma unroll
    for (int n = 0; n < 8; ++n) {
      int row = n * 16 + rl;
      half8 bdummy;  // (unused type anchor)
      short8 b = *(const short8*)(Bsp + row * 512
                                  + ((k * 64 + rq * 16) ^ ((row & 7) << 4)));
      acc[0][n] = MFMA16B(a[0][k], b, acc[0][n]);
      acc[1][n] = MFMA16B(a[1][k], b, acc[1][n]);
      (void)bdummy;
    }
  }

  float* dst = outneg + (size_t)p * U_DIM * F_DIM;
  #pragma unroll
  for (int m = 0; m < 2; ++m)
    #pragma unroll
    for (int n = 0; n < 8; ++n)
      #pragma unroll
      for (int i = 0; i < 4; ++i) {
        int u = wid * 32 + m * 16 + rq * 4 + i;
        int f = n0 + n * 16 + rl;
        dst[(size_t)u * F_DIM + f] = acc[m][n][i];
      }
}

// ---------------------------------------------------------------------------
extern "C" void kernel_launch(void* const* d_in, const int* in_sizes, int n_in,
                              void* d_out, int out_size, void* d_ws, size_t ws_size,
                              hipStream_t stream) {
  const float* fu = (const float*)d_in[0];
  const float* fv = (const float*)d_in[1];
  float* out = (float*)d_out;
  char* ws = (char*)d_ws;

  // ws: vv 8KB | score 1MB | fvT 51.4MB | vvpart 1.6MB | part (splitk*2MB)
  float* vv = (float*)ws;
  unsigned short* score = (unsigned short*)(ws + 8192);
  unsigned short* fvT = (unsigned short*)(ws + 8192 + 1048576);
  size_t vvpartBase = 8192 + 1048576 + (size_t)P_DIM * F_DIM * V_DIM * 2;
  float* vvpart = (float*)(ws + vvpartBase);
  size_t partBase = vvpartBase + (size_t)(F_DIM / 64) * P_DIM * V_DIM * 4;
  float* part = (float*)(ws + partBase);

  const size_t puv4 = (size_t)P_DIM * U_DIM * V_DIM * 4;
  int splitk = 1;
  const int cands[5] = {14, 7, 4, 2, 1};
  for (int i = 0; i < 5; ++i) {
    if (partBase + (size_t)cands[i] * puv4 <= ws_size) { splitk = cands[i]; break; }
  }
  int chunk = F_DIM / splitk;                // multiple of 64 for all candidates

  prep_fv<<<dim3(F_DIM / 64, V_DIM / 64, P_DIM), 256, 0, stream>>>(fv, fvT, vvpart);
  vv_reduce<<<P_DIM * 4, 256, 0, stream>>>(vvpart, vv);
  int n4 = (P_DIM * U_DIM * F_DIM) / 4;
  copy_kernel<<<2048, 256, 0, stream>>>((const float4*)fu, (float4*)out, n4);
  uv_gemm<<<splitk * 32, 256, 0, stream>>>(fu, fv, part, splitk, chunk);
  reduce_softmax<<<P_DIM * U_DIM, 256, 0, stream>>>(part, vv, score, splitk);
  pv_gemm<<<dim3(F_DIM / 128, P_DIM), 512, 0, stream>>>(
      score, fvT, out + (size_t)P_DIM * U_DIM * F_DIM);
}